// Round 10
// baseline (95.853 us; speedup 1.0000x reference)
//
#include <hip/hip_runtime.h>

// Forward collapse:
//   c = y[b]; k = argmax_k(logits[c,k] + gumbel[c,b,k]) (first max)
//   x[b,:] = L[c,k] @ z[b,:] + m[c,k,:]
//
// Round 10: ONE kernel (round-5 fusion retried at round-9 occupancy).
// Grid (100 ck, 2 jh, 2 sample-halves), 256 thr, 62 KB LDS -> 2 blocks/CU,
// 8 waves/CU, 400 blocks on 200 CUs. Each block:
//   1. stages rotated L-half (32 KB),
//   2. scans its 4096-sample half of y (uint4), gumbel-argmax for y==c
//      candidates (~410), builds LDS sample list (~41),
//   3. runs the verified 4j x 4s register-tiled GEMV (pitched zs rows).

#define N_Z 128
#define N_COMP 10
#define N_CLASSES 10
#define N_CK (N_CLASSES * N_COMP)
#define TB 56            // samples per chunk
#define ZPITCH 132       // zs row pitch in floats (breaks power-of-2 bank stride)
#define LIST_CAP 256

__global__ __launch_bounds__(256) void k_fused(
    const float* __restrict__ z, const int* __restrict__ y,
    const float* __restrict__ gumbel, const float* __restrict__ m,
    const float* __restrict__ L, const float* __restrict__ logits,
    float* __restrict__ out, int bs)
{
    const int ck = blockIdx.x;
    const int jh = blockIdx.y;   // j range [jh*64, jh*64+64)
    const int bh = blockIdx.z;   // sample half
    const int c  = ck / N_COMP;
    const int kk = ck - c * N_COMP;

    __shared__ __align__(16) float Ls[64 * 128];      // 32 KB rotated half
    __shared__ __align__(16) float zs[TB * ZPITCH];   // 28.9 KB pitched z rows
    __shared__ int list[LIST_CAP];                    // 1 KB
    __shared__ int cnt;

    const int t = threadIdx.x;
    if (t == 0) cnt = 0;

    // class logits (wave-uniform -> scalar loads)
    float lg[N_COMP];
    #pragma unroll
    for (int k2 = 0; k2 < N_COMP; ++k2) lg[k2] = logits[c * N_COMP + k2];

    // ---- stage L half (64 rows x 128 = 2048 float4s, 256 thr x 8) ----
    {
        const float4* Lg4 = (const float4*)(L + ((size_t)ck * N_Z + jh * 64) * N_Z);
        #pragma unroll
        for (int p = 0; p < 8; ++p) {
            int f  = p * 256 + t;      // float4 index in the 64x128 half
            int jl = f >> 5;           // local row 0..63
            int fi = f & 31;
            float4 v = Lg4[f];
            int col = ((fi << 2) + 4 * jl) & 127;
            *(float4*)&Ls[jl * 128 + col] = v;
        }
    }
    __syncthreads();   // cnt=0 visible; Ls staged

    // ---- fused selection: scan this half of y, argmax gumbel for y==c ----
    {
        const int half = bs >> 1;                         // 4096
        const uint4* y4 = (const uint4*)(y + bh * half);  // 4 samples per load
        #pragma unroll
        for (int p = 0; p < 4; ++p) {
            int idx = p * 256 + t;                        // 0..1023
            uint4 v = y4[idx];
            int b0 = bh * half + idx * 4;
            int ys[4] = {(int)v.x, (int)v.y, (int)v.z, (int)v.w};
            #pragma unroll
            for (int e = 0; e < 4; ++e) {
                if (ys[e] == c) {
                    int b = b0 + e;
                    const float* g = gumbel + ((size_t)c * bs + b) * N_COMP;  // 8-B aligned
                    float2 g01 = *(const float2*)(g + 0);
                    float2 g23 = *(const float2*)(g + 2);
                    float2 g45 = *(const float2*)(g + 4);
                    float2 g67 = *(const float2*)(g + 6);
                    float2 g89 = *(const float2*)(g + 8);
                    float sc[N_COMP] = {
                        g01.x + lg[0], g01.y + lg[1], g23.x + lg[2], g23.y + lg[3],
                        g45.x + lg[4], g45.y + lg[5], g67.x + lg[6], g67.y + lg[7],
                        g89.x + lg[8], g89.y + lg[9] };
                    float best = sc[0];
                    int bi = 0;
                    #pragma unroll
                    for (int k2 = 1; k2 < N_COMP; ++k2)
                        if (sc[k2] > best) { best = sc[k2]; bi = k2; }  // first-max
                    if (bi == kk) {
                        int p2 = atomicAdd(&cnt, 1);
                        if (p2 < LIST_CAP) list[p2] = b;
                    }
                }
            }
        }
    }
    __syncthreads();

    const int n = min(cnt, LIST_CAP);   // ~41 typical

    const int jg  = t & 15;    // 16 j-groups, local rows jl = jg + 16r (r<4)
    const int sg  = t >> 4;    // 16 s-groups x 4 samples
    const int sl4 = sg << 2;

    for (int s0 = 0; s0 < n; s0 += TB) {
        const int ns = min(TB, n - s0);

        // ---- stage z rows: zs[sl*ZPITCH + i] (TB*32 = 1792 f4, 256 thr x 7) ----
        #pragma unroll
        for (int p = 0; p < 7; ++p) {
            int f  = p * 256 + t;        // 0..1791
            int sl = f >> 5;             // 0..55
            int fi = f & 31;
            int samp = list[s0 + (sl < ns ? sl : 0)];
            float4 v = *(const float4*)(z + (size_t)samp * N_Z + fi * 4);
            *(float4*)&zs[sl * ZPITCH + fi * 4] = v;
        }
        __syncthreads();

        if (sl4 < ns) {
            float acc[4][4] = {};
            #pragma unroll 2
            for (int i = 0; i < N_Z; i += 4) {
                float4 zv[4];
                #pragma unroll
                for (int s = 0; s < 4; ++s)
                    zv[s] = *(const float4*)&zs[(sl4 + s) * ZPITCH + i];
                #pragma unroll
                for (int r = 0; r < 4; ++r) {
                    int jl  = jg + 16 * r;
                    int col = (i + 4 * jl) & 127;
                    float4 lv = *(const float4*)&Ls[jl * 128 + col];
                    acc[r][0] += lv.x * zv[0].x + lv.y * zv[0].y + lv.z * zv[0].z + lv.w * zv[0].w;
                    acc[r][1] += lv.x * zv[1].x + lv.y * zv[1].y + lv.z * zv[1].z + lv.w * zv[1].w;
                    acc[r][2] += lv.x * zv[2].x + lv.y * zv[2].y + lv.z * zv[2].z + lv.w * zv[2].w;
                    acc[r][3] += lv.x * zv[3].x + lv.y * zv[3].y + lv.z * zv[3].z + lv.w * zv[3].w;
                }
            }
            // ---- epilogue: add m, scatter ----
            #pragma unroll
            for (int r = 0; r < 4; ++r) {
                int j = jh * 64 + jg + 16 * r;
                float mm = m[ck * N_Z + j];
                #pragma unroll
                for (int s = 0; s < 4; ++s) {
                    int sl = sl4 + s;
                    if (sl < ns) {
                        int samp = list[s0 + sl];
                        out[(size_t)samp * N_Z + j] = acc[r][s] + mm;
                    }
                }
            }
        }
        __syncthreads();   // before next chunk overwrites zs
    }
}

extern "C" void kernel_launch(void* const* d_in, const int* in_sizes, int n_in,
                              void* d_out, int out_size, void* d_ws, size_t ws_size,
                              hipStream_t stream)
{
    const float* z      = (const float*)d_in[0];
    const int*   y      = (const int*)d_in[1];
    const float* gumbel = (const float*)d_in[2];
    const float* m      = (const float*)d_in[3];
    const float* L      = (const float*)d_in[4];
    const float* logits = (const float*)d_in[5];
    float* out = (float*)d_out;

    const int bs = in_sizes[0] / N_Z;  // 8192

    k_fused<<<dim3(N_CK, 2, 2), 256, 0, stream>>>(z, y, gumbel, m, L, logits, out, bs);
}

// Round 11
// 84.832 us; speedup vs baseline: 1.1299x; 1.1299x over previous
//
#include <hip/hip_runtime.h>

// Forward collapse:
//   c = y[b]; k = argmax_k(logits[c,k] + gumbel[c,b,k]) (first max)
//   x[b,:] = L[c,k] @ z[b,:] + m[c,k,:]
//
// Round 11: R9 two-node structure, but the GEMV core replaced by bf16 MFMA
// (mfma_f32_16x16x32_bf16, fp32 accumulate). Selection stays fp32-exact.
// Grid (100 ck, 2 jh), 256 thr, ~41 KB LDS -> 3 blocks/CU.
//   A = L-half (M=64 j), B = z rows (N = samples), K = 128.
//   Frag layouts (guide §3, m89/m91/m120): A[m=lane&15][k=quad*8+j],
//   B[k=quad*8+j][n=lane&15] (z row-major supplies exactly this),
//   D col=lane&15 (sample), row=quad*4+reg (j) -> float4 epilogue stores.

#define N_Z 128
#define N_COMP 10
#define N_CLASSES 10
#define N_CK (N_CLASSES * N_COMP)
#define ZCAP 96          // z rows per chunk (n ~ 82 +- 9; chunk loop covers overflow)
#define LIST_CAP 256

typedef __attribute__((ext_vector_type(4))) __bf16 bf16x4;
typedef __attribute__((ext_vector_type(8))) __bf16 bf16x8;
typedef __attribute__((ext_vector_type(4))) float f32x4;

// ---------------- K1: per-sample component select (atomic-free, fp32 exact) ----
__global__ __launch_bounds__(64) void k_select(
    const int* __restrict__ y, const float* __restrict__ gumbel,
    const float* __restrict__ logits, unsigned char* __restrict__ ck_arr, int bs)
{
    int b = blockIdx.x * 64 + threadIdx.x;
    if (b >= bs) return;
    int c = y[b];
    const float* g  = gumbel + ((size_t)c * bs + b) * N_COMP;
    const float* lg = logits + c * N_COMP;
    float best = g[0] + lg[0];
    int bi = 0;
    #pragma unroll
    for (int k = 1; k < N_COMP; ++k) {
        float s = g[k] + lg[k];
        if (s > best) { best = s; bi = k; }  // strict > == first-max (jnp.argmax)
    }
    ck_arr[b] = (unsigned char)(c * N_COMP + bi);
}

// ---------------- K2: per-bucket MFMA GEMM ----------------
__global__ __launch_bounds__(256) void k_mfma(
    const float* __restrict__ z, const float* __restrict__ m,
    const float* __restrict__ L, const unsigned char* __restrict__ ck_arr,
    float* __restrict__ out, int bs)
{
    const int ck = blockIdx.x;
    const int jh = blockIdx.y;   // j range [jh*64, jh*64+64)

    __shared__ __align__(16) __bf16 Lsb[64 * 128];   // 16 KB, row-major [jl][i]
    __shared__ __align__(16) __bf16 zsb[ZCAP * 128]; // 24 KB, row-major [sl][i]
    __shared__ int list[LIST_CAP];                   // 1 KB
    __shared__ int cnt;

    const int t = threadIdx.x;
    if (t == 0) cnt = 0;

    // ---- stage + convert L half: 64x128 fp32 = 2048 float4s, 8/thread ----
    {
        const float4* Lg4 = (const float4*)(L + ((size_t)ck * N_Z + jh * 64) * N_Z);
        #pragma unroll
        for (int p = 0; p < 8; ++p) {
            int f = p * 256 + t;              // float4 index; row = f>>5, col4 = f&31
            float4 v = Lg4[f];
            bf16x4 b4 = { (__bf16)v.x, (__bf16)v.y, (__bf16)v.z, (__bf16)v.w };
            *(bf16x4*)&Lsb[f * 4] = b4;       // 8-B store, row-major
        }
    }
    __syncthreads();   // cnt=0 visible; Lsb staged

    // ---- scan ck_arr (8 KB = 512 uint4, 2/thread) -> LDS match list ----
    {
        const uint4* ck4 = (const uint4*)ck_arr;
        #pragma unroll
        for (int p = 0; p < 2; ++p) {
            int idx = p * 256 + t;
            uint4 v = ck4[idx];
            int b0 = idx * 16;
            unsigned w[4] = {v.x, v.y, v.z, v.w};
            #pragma unroll
            for (int q = 0; q < 4; ++q) {
                #pragma unroll
                for (int e = 0; e < 4; ++e) {
                    if (((w[q] >> (8 * e)) & 0xFFu) == (unsigned)ck) {
                        int p2 = atomicAdd(&cnt, 1);
                        if (p2 < LIST_CAP) list[p2] = b0 + q * 4 + e;
                    }
                }
            }
        }
    }
    __syncthreads();

    const int n = min(cnt, LIST_CAP);   // ~82 typical

    const int wv   = t >> 6;        // wave 0..3
    const int lane = t & 63;
    const int mn   = lane & 15;     // A row / B col / D col index
    const int quad = lane >> 4;     // 0..3

    for (int s0 = 0; s0 < n; s0 += ZCAP) {
        const int ns = min(ZCAP, n - s0);

        // ---- stage + convert z rows: ns x 128 fp32, up to 3072 float4s ----
        #pragma unroll
        for (int p = 0; p < 12; ++p) {
            int f   = p * 256 + t;          // float4 index; row = f>>5, col4 = f&31
            int row = f >> 5;
            if (row < ns) {
                int samp = list[s0 + row];
                float4 v = *(const float4*)(z + (size_t)samp * N_Z + (f & 31) * 4);
                bf16x4 b4 = { (__bf16)v.x, (__bf16)v.y, (__bf16)v.z, (__bf16)v.w };
                *(bf16x4*)&zsb[row * 128 + (f & 31) * 4] = b4;
            }
        }
        __syncthreads();

        // ---- MFMA compute: wave wv handles N-tiles wv and wv+4 ----
        const int ntiles = (ns + 15) >> 4;
        #pragma unroll
        for (int half = 0; half < 2; ++half) {
            int nt = wv + half * 4;
            if (nt >= ntiles) break;          // wave-uniform
            int nb = nt * 16;
            int srow = nb + mn;               // sample row (may be >= ns: garbage ok)

            bf16x8 bf[4];
            #pragma unroll
            for (int ks = 0; ks < 4; ++ks)
                bf[ks] = *(const bf16x8*)&zsb[srow * 128 + ks * 32 + quad * 8];

            #pragma unroll
            for (int mt = 0; mt < 4; ++mt) {
                f32x4 acc = {0.f, 0.f, 0.f, 0.f};
                #pragma unroll
                for (int ks = 0; ks < 4; ++ks) {
                    bf16x8 af = *(const bf16x8*)&Lsb[(mt * 16 + mn) * 128 + ks * 32 + quad * 8];
                    acc = __builtin_amdgcn_mfma_f32_16x16x32_bf16(af, bf[ks], acc, 0, 0, 0);
                }
                // ---- epilogue: this lane owns sample col mn, rows quad*4+0..3 ----
                int sidx = nb + mn;
                if (sidx < ns) {
                    int samp = list[s0 + sidx];
                    int j0 = jh * 64 + mt * 16 + quad * 4;
                    float4 mv = *(const float4*)(m + ck * N_Z + j0);
                    float4 o;
                    o.x = acc.x + mv.x;
                    o.y = acc.y + mv.y;
                    o.z = acc.z + mv.z;
                    o.w = acc.w + mv.w;
                    *(float4*)(out + (size_t)samp * N_Z + j0) = o;
                }
            }
        }
        __syncthreads();   // before next chunk overwrites zsb
    }
}

extern "C" void kernel_launch(void* const* d_in, const int* in_sizes, int n_in,
                              void* d_out, int out_size, void* d_ws, size_t ws_size,
                              hipStream_t stream)
{
    const float* z      = (const float*)d_in[0];
    const int*   y      = (const int*)d_in[1];
    const float* gumbel = (const float*)d_in[2];
    const float* m      = (const float*)d_in[3];
    const float* L      = (const float*)d_in[4];
    const float* logits = (const float*)d_in[5];
    float* out = (float*)d_out;

    const int bs = in_sizes[0] / N_Z;  // 8192

    unsigned char* ck_arr = (unsigned char*)d_ws;   // bs bytes

    k_select<<<(bs + 63) / 64, 64, 0, stream>>>(y, gumbel, logits, ck_arr, bs);
    k_mfma<<<dim3(N_CK, 2), 256, 0, stream>>>(z, m, L, ck_arr, out, bs);
}